// Round 5
// baseline (66.587 us; speedup 1.0000x reference)
//
#include <hip/hip_runtime.h>
#include <stdint.h>

#define N_TOT 8192
#define DIM   256
#define BHALF 4096
#define BM    256           // rows per block (4 waves x 64 rows each)
#define CT    64            // col-tile width
#define NC    16            // col chunks (grid.y)
#define CW    (N_TOT / NC)  // 512 cols per block
#define NTILE (CW / CT)     // 8 tiles

#define SCALEF 2.8853900817779268f   // (1/temp) * log2(e) = 2*log2(e)
#define LN2F   0.69314718055994531f
#define SHIFT2 200.0f                // fixed base-2 shift (no running max)

typedef __attribute__((ext_vector_type(8))) short bf16x8;
typedef __attribute__((ext_vector_type(16))) float f32x16;

typedef const __attribute__((address_space(1))) void* gas_ptr;
typedef __attribute__((address_space(3))) void* lds_ptr;

#if __has_builtin(__builtin_amdgcn_exp2f)
__device__ inline float exp2v(float x) { return __builtin_amdgcn_exp2f(x); }
#else
__device__ inline float exp2v(float x) { return exp2f(x); }
#endif

__device__ inline float bf2f(ushort u) { return __uint_as_float(((uint32_t)u) << 16); }

__device__ inline ushort f2bf(float f) {
  uint32_t u = __float_as_uint(f);
  u = (u + 0x7fffu + ((u >> 16) & 1u)) >> 16;   // RNE
  return (ushort)u;
}

// ---- 1. fp32 -> bf16 conversion: hb[0..B-1]=h_i, hb[B..2B-1]=h_j ----
__global__ void conv_kernel(const float* __restrict__ hi, const float* __restrict__ hj,
                            ushort* __restrict__ hb) {
  int t = blockIdx.x * blockDim.x + threadIdx.x;      // float4 index
  const int half4 = BHALF * DIM / 4;                  // 262144
  float4 v = (t < half4) ? ((const float4*)hi)[t] : ((const float4*)hj)[t - half4];
  ushort4 o;
  o.x = f2bf(v.x); o.y = f2bf(v.y); o.z = f2bf(v.z); o.w = f2bf(v.w);
  ((ushort4*)hb)[t] = o;
}

// ---- 2. positive logits (base-2 domain): pos2[i] = SCALE * dot(hb[i], hb[i^B]) ----
__global__ void pos_kernel(const ushort* __restrict__ hb, float* __restrict__ pos2) {
  int gw = (blockIdx.x * blockDim.x + threadIdx.x) >> 6;  // one wave per row
  int l = threadIdx.x & 63;
  if (gw >= N_TOT) return;
  int j = (gw < BHALF) ? gw + BHALF : gw - BHALF;
  const ushort4* a = (const ushort4*)(hb + (size_t)gw * DIM);
  const ushort4* b = (const ushort4*)(hb + (size_t)j * DIM);
  ushort4 av = a[l], bv = b[l];
  float acc = bf2f(av.x) * bf2f(bv.x) + bf2f(av.y) * bf2f(bv.y)
            + bf2f(av.z) * bf2f(bv.z) + bf2f(av.w) * bf2f(bv.w);
  #pragma unroll
  for (int d = 1; d < 64; d <<= 1) acc += __shfl_xor(acc, d, 64);
  if (l == 0) pos2[gw] = acc * SCALEF;
}

// ---- 3. flash-LSE stage 1: 32x32x16 MFMA, fixed-shift sum of exp2, 64 rows/wave ----
__global__ __launch_bounds__(256, 1)
void lse_stage1(const ushort* __restrict__ hb, float* __restrict__ wsum) {
  const int tid = threadIdx.x;
  const int w  = tid >> 6;        // wave 0..3
  const int l  = tid & 63;
  const int cl = l & 31;          // col-lane within 32
  const int hh = l >> 5;          // half: 0/1
  const int row0  = blockIdx.x * BM + w * 64;   // this wave's 64 rows
  const int cbase = blockIdx.y * CW;

  __shared__ ushort Bt[2][CT * DIM];   // 2 x 32 KB, XOR-swizzled rows (row&15)<<4

  // A fragments: 2 row-frags (32 rows) x 16 k-chunks (k=16 each) = 128 VGPR
  // lane mapping: row = cl (+32*r), k = q*16 + hh*8 + j  (A/B symmetric k-map)
  bf16x8 afrag[2][16];
  #pragma unroll
  for (int r = 0; r < 2; ++r) {
    const ushort* ap = hb + (size_t)(row0 + r * 32 + cl) * DIM + hh * 8;
    #pragma unroll
    for (int q = 0; q < 16; ++q) afrag[r][q] = *(const bf16x8*)(ap + q * 16);
  }

  float s[32];
  #pragma unroll
  for (int i = 0; i < 32; ++i) s[i] = 0.0f;
  const float NEGINF = -__builtin_inff();

  // stage tile t into buffer buf: linear LDS dest, inverse-swizzled global source
  auto stage = [&](int buf, int t) {
    const int c0 = cbase + t * CT;
    #pragma unroll
    for (int q = 0; q < 8; ++q) {
      int a    = w * 8192 + q * 1024 + l * 16;       // linear LDS byte offset in buf
      int trow = a >> 9;                             // 0..63
      int kb   = (a & 511) ^ ((trow & 15) << 4);     // global k-byte for this slot
      const void* g = (const void*)((const char*)hb + ((size_t)(c0 + trow) * DIM) * 2 + kb);
      __builtin_amdgcn_global_load_lds((gas_ptr)g,
                                       (lds_ptr)((char*)&Bt[buf][0] + w * 8192 + q * 1024),
                                       16, 0, 0);
    }
  };

  // prologue
  stage(0, 0);
  asm volatile("s_waitcnt vmcnt(0)" ::: "memory");
  __syncthreads();

  for (int t = 0; t < NTILE; ++t) {
    const int cur = t & 1;
    const int c0  = cbase + t * CT;
    if (t + 1 < NTILE) stage(cur ^ 1, t + 1);   // async prefetch of next tile

    const bool hasdiag = (c0 < row0 + 64) && (row0 < c0 + CT);  // wave-uniform

    // two col-fragments processed serially: acc live range = 32 regs
    #pragma unroll
    for (int f = 0; f < 2; ++f) {
      f32x16 acc0 = {0.f}, acc1 = {0.f};
      #pragma unroll
      for (int e = 0; e < 16; ++e) { acc0[e] = 0.f; acc1[e] = 0.f; }

      const int  brow  = f * 32 + cl;                 // B storage row (= global col within tile)
      const char* bbase = (const char*)&Bt[cur][0] + brow * 512;
      const int  kxor  = (brow & 15) << 4;

      __builtin_amdgcn_s_setprio(1);
      #pragma unroll
      for (int q = 0; q < 16; ++q) {
        const int kb = (q * 32 + hh * 16) ^ kxor;
        bf16x8 bfr = *(const bf16x8*)(bbase + kb);
        acc0 = __builtin_amdgcn_mfma_f32_32x32x16_bf16(afrag[0][q], bfr, acc0, 0, 0, 0);
        acc1 = __builtin_amdgcn_mfma_f32_32x32x16_bf16(afrag[1][q], bfr, acc1, 0, 0, 0);
      }
      __builtin_amdgcn_s_setprio(0);

      // epilogue: fixed-shift exp2 accumulate
      // C/D layout (m74/m101): col = cl (+32*f), row = (e&3) + 8*(e>>2) + 4*hh (+32*r)
      const int gcol = c0 + f * 32 + cl;
      #pragma unroll
      for (int e = 0; e < 16; ++e) {
        float v0 = acc0[e], v1 = acc1[e];
        if (hasdiag) {
          const int rr = (e & 3) + 8 * (e >> 2) + 4 * hh;
          v0 = (row0 + rr      == gcol) ? NEGINF : v0;
          v1 = (row0 + 32 + rr == gcol) ? NEGINF : v1;
        }
        s[e]      += exp2v(__builtin_fmaf(v0, SCALEF, -SHIFT2));
        s[16 + e] += exp2v(__builtin_fmaf(v1, SCALEF, -SHIFT2));
      }
    }

    asm volatile("s_waitcnt vmcnt(0)" ::: "memory");  // prefetch landed
    __syncthreads();                                  // all waves done with cur
  }

  // sum s across the 32 col-lanes sharing each row (d<32 keeps lane-halves intact)
  #pragma unroll
  for (int i = 0; i < 32; ++i) {
    #pragma unroll
    for (int d = 1; d < 32; d <<= 1) s[i] += __shfl_xor(s[i], d, 64);
  }

  if (cl == 0) {
    #pragma unroll
    for (int r = 0; r < 2; ++r)
      #pragma unroll
      for (int e = 0; e < 16; ++e) {
        int grow = row0 + r * 32 + (e & 3) + 8 * (e >> 2) + 4 * hh;
        wsum[blockIdx.y * N_TOT + grow] = s[r * 16 + e];
      }
  }
}

// ---- 4. per-row chunk merge + loss partial per block ----
__global__ void finish_kernel(const float* __restrict__ wsum,
                              const float* __restrict__ pos2, float* __restrict__ partial) {
  const int i = blockIdx.x * blockDim.x + threadIdx.x;   // row, exactly 8192 threads
  float S = 0.f;
  #pragma unroll
  for (int c = 0; c < NC; ++c) S += wsum[c * N_TOT + i];
  float lse2 = SHIFT2 + log2f(S);
  float contrib = (lse2 - pos2[i]) * (LN2F / (float)N_TOT);

  #pragma unroll
  for (int d = 32; d >= 1; d >>= 1) contrib += __shfl_down(contrib, d, 64);
  __shared__ float red[4];
  if ((threadIdx.x & 63) == 0) red[threadIdx.x >> 6] = contrib;
  __syncthreads();
  if (threadIdx.x == 0) partial[blockIdx.x] = red[0] + red[1] + red[2] + red[3];
}

__global__ void final_kernel(const float* __restrict__ partial, float* __restrict__ out) {
  int l = threadIdx.x;
  float v = (l < 32) ? partial[l] : 0.f;
  #pragma unroll
  for (int d = 32; d >= 1; d >>= 1) v += __shfl_down(v, d, 64);
  if (l == 0) out[0] = v;
}

extern "C" void kernel_launch(void* const* d_in, const int* in_sizes, int n_in,
                              void* d_out, int out_size, void* d_ws, size_t ws_size,
                              hipStream_t stream) {
  const float* hi = (const float*)d_in[0];
  const float* hj = (const float*)d_in[1];
  float* out = (float*)d_out;
  char* ws = (char*)d_ws;

  ushort* hb    = (ushort*)(ws);                       // 4 MB bf16 h
  float*  wsum  = (float*)(ws + 4194304);              // 512 KB  [NC][N] shifted sums
  float*  pos2  = (float*)(ws + 4194304 + 524288);     // 32 KB   positive logits
  float*  part  = (float*)(ws + 4194304 + 524288 + 32768); // 128 B block partials

  conv_kernel<<<N_TOT * DIM / 4 / 256, 256, 0, stream>>>(hi, hj, hb);
  pos_kernel<<<N_TOT / 4, 256, 0, stream>>>(hb, pos2);
  dim3 g1(N_TOT / BM, NC);
  lse_stage1<<<g1, 256, 0, stream>>>(hb, wsum);
  finish_kernel<<<N_TOT / 256, 256, 0, stream>>>(wsum, pos2, part);
  final_kernel<<<1, 64, 0, stream>>>(part, out);
}

// Round 6
// 58.139 us; speedup vs baseline: 1.1453x; 1.1453x over previous
//
#include <hip/hip_runtime.h>
#include <stdint.h>

#define N_TOT 8192
#define DIM   256
#define BHALF 4096
#define BM    256           // rows per block (4 waves x 64 rows each)
#define CT    32            // col-tile width (16 KB tiles)
#define NC    16            // col chunks (grid.y)
#define CW    (N_TOT / NC)  // 512 cols per block
#define NTILE (CW / CT)     // 16 tiles

#define SCALEF 2.8853900817779268f   // (1/temp) * log2(e) = 2*log2(e)
#define LN2F   0.69314718055994531f
#define SHIFT2 200.0f                // fixed base-2 shift (no running max)

typedef __attribute__((ext_vector_type(8))) short bf16x8;
typedef __attribute__((ext_vector_type(16))) float f32x16;

typedef const __attribute__((address_space(1))) void* gas_ptr;
typedef __attribute__((address_space(3))) void* lds_ptr;

#if __has_builtin(__builtin_amdgcn_exp2f)
__device__ inline float exp2v(float x) { return __builtin_amdgcn_exp2f(x); }
#else
__device__ inline float exp2v(float x) { return exp2f(x); }
#endif

__device__ inline float bf2f(ushort u) { return __uint_as_float(((uint32_t)u) << 16); }

__device__ inline ushort f2bf(float f) {
  uint32_t u = __float_as_uint(f);
  u = (u + 0x7fffu + ((u >> 16) & 1u)) >> 16;   // RNE
  return (ushort)u;
}

// ---- 1. fp32 -> bf16 conversion: hb[0..B-1]=h_i, hb[B..2B-1]=h_j ----
__global__ void conv_kernel(const float* __restrict__ hi, const float* __restrict__ hj,
                            ushort* __restrict__ hb) {
  int t = blockIdx.x * blockDim.x + threadIdx.x;      // float4 index
  const int half4 = BHALF * DIM / 4;                  // 262144
  float4 v = (t < half4) ? ((const float4*)hi)[t] : ((const float4*)hj)[t - half4];
  ushort4 o;
  o.x = f2bf(v.x); o.y = f2bf(v.y); o.z = f2bf(v.z); o.w = f2bf(v.w);
  ((ushort4*)hb)[t] = o;
}

// ---- 2. positive logits (base-2 domain): pos2[i] = SCALE * dot(hb[i], hb[i^B]) ----
__global__ void pos_kernel(const ushort* __restrict__ hb, float* __restrict__ pos2) {
  int gw = (blockIdx.x * blockDim.x + threadIdx.x) >> 6;  // one wave per row
  int l = threadIdx.x & 63;
  if (gw >= N_TOT) return;
  int j = (gw < BHALF) ? gw + BHALF : gw - BHALF;
  const ushort4* a = (const ushort4*)(hb + (size_t)gw * DIM);
  const ushort4* b = (const ushort4*)(hb + (size_t)j * DIM);
  ushort4 av = a[l], bv = b[l];
  float acc = bf2f(av.x) * bf2f(bv.x) + bf2f(av.y) * bf2f(bv.y)
            + bf2f(av.z) * bf2f(bv.z) + bf2f(av.w) * bf2f(bv.w);
  #pragma unroll
  for (int d = 1; d < 64; d <<= 1) acc += __shfl_xor(acc, d, 64);
  if (l == 0) pos2[gw] = acc * SCALEF;
}

// ---- 3. flash-LSE stage 1: 32x32x16 MFMA, tri-buffered LDS, counted vmcnt ----
__global__ __launch_bounds__(256, 2)
void lse_stage1(const ushort* __restrict__ hb, float* __restrict__ wsum) {
  const int tid = threadIdx.x;
  const int w  = tid >> 6;        // wave 0..3
  const int l  = tid & 63;
  const int cl = l & 31;          // col-lane within 32
  const int hh = l >> 5;          // half: 0/1
  const int row0  = blockIdx.x * BM + w * 64;   // this wave's 64 rows
  const int cbase = blockIdx.y * CW;

  __shared__ ushort Bt[3][CT * DIM];   // 3 x 16 KB, XOR-swizzled rows (row&15)<<4

  // A fragments: 2 row-frags (32 rows) x 16 k-chunks (k=16 each) = 128 VGPR
  bf16x8 afrag[2][16];
  #pragma unroll
  for (int r = 0; r < 2; ++r) {
    const ushort* ap = hb + (size_t)(row0 + r * 32 + cl) * DIM + hh * 8;
    #pragma unroll
    for (int q = 0; q < 16; ++q) afrag[r][q] = *(const bf16x8*)(ap + q * 16);
  }

  float s[32];
  #pragma unroll
  for (int i = 0; i < 32; ++i) s[i] = 0.0f;
  const float NEGINF = -__builtin_inff();

  // stage tile t (16 KB) into buffer buf: 4 global_load_lds per wave
  auto stage = [&](int buf, int t) {
    const int c0 = cbase + t * CT;
    #pragma unroll
    for (int q = 0; q < 4; ++q) {
      int a    = w * 4096 + q * 1024 + l * 16;       // linear LDS byte offset in buf
      int trow = a >> 9;                             // 0..31
      int kb   = (a & 511) ^ ((trow & 15) << 4);     // global k-byte for this slot
      const void* g = (const void*)((const char*)hb + ((size_t)(c0 + trow) * DIM) * 2 + kb);
      __builtin_amdgcn_global_load_lds((gas_ptr)g,
                                       (lds_ptr)((char*)&Bt[buf][0] + w * 4096 + q * 1024),
                                       16, 0, 0);
    }
  };

  // prologue: 2 tiles in flight
  stage(0, 0);
  stage(1, 1);
  asm volatile("s_waitcnt vmcnt(4)" ::: "memory");   // tile 0 landed (tile 1 in flight)
  __builtin_amdgcn_s_barrier();

  for (int t = 0; t < NTILE; ++t) {
    const int cur = t % 3;
    const int c0  = cbase + t * CT;
    if (t + 2 < NTILE) stage((t + 2) % 3, t + 2);    // keep 2 tiles in flight

    const bool hasdiag = (c0 < row0 + 64) && (row0 < c0 + CT);  // wave-uniform

    f32x16 acc0, acc1;
    #pragma unroll
    for (int e = 0; e < 16; ++e) { acc0[e] = 0.f; acc1[e] = 0.f; }

    const char* bbase = (const char*)&Bt[cur][0] + cl * 512;
    const int   kxor  = (cl & 15) << 4;

    #pragma unroll
    for (int q = 0; q < 16; ++q) {
      const int kb = (q * 32 + hh * 16) ^ kxor;
      bf16x8 bfr = *(const bf16x8*)(bbase + kb);
      acc0 = __builtin_amdgcn_mfma_f32_32x32x16_bf16(afrag[0][q], bfr, acc0, 0, 0, 0);
      acc1 = __builtin_amdgcn_mfma_f32_32x32x16_bf16(afrag[1][q], bfr, acc1, 0, 0, 0);
    }

    // epilogue: fixed-shift exp2 accumulate
    // C/D layout (m74/m101): col = cl, row = (e&3) + 8*(e>>2) + 4*hh (+32*r)
    const int gcol = c0 + cl;
    #pragma unroll
    for (int e = 0; e < 16; ++e) {
      float v0 = acc0[e], v1 = acc1[e];
      if (hasdiag) {
        const int rr = (e & 3) + 8 * (e >> 2) + 4 * hh;
        v0 = (row0 + rr      == gcol) ? NEGINF : v0;
        v1 = (row0 + 32 + rr == gcol) ? NEGINF : v1;
      }
      s[e]      += exp2v(__builtin_fmaf(v0, SCALEF, -SHIFT2));
      s[16 + e] += exp2v(__builtin_fmaf(v1, SCALEF, -SHIFT2));
    }

    // counted drain: wait only for tile t+1's loads; t+2's stay in flight
    if (t + 1 < NTILE) {
      if (t + 2 < NTILE) asm volatile("s_waitcnt vmcnt(4)" ::: "memory");
      else               asm volatile("s_waitcnt vmcnt(0)" ::: "memory");
      __builtin_amdgcn_s_barrier();
    }
  }

  // sum s across the 32 col-lanes sharing each row (d<32 keeps lane-halves intact)
  #pragma unroll
  for (int i = 0; i < 32; ++i) {
    #pragma unroll
    for (int d = 1; d < 32; d <<= 1) s[i] += __shfl_xor(s[i], d, 64);
  }

  if (cl == 0) {
    #pragma unroll
    for (int r = 0; r < 2; ++r)
      #pragma unroll
      for (int e = 0; e < 16; ++e) {
        int grow = row0 + r * 32 + (e & 3) + 8 * (e >> 2) + 4 * hh;
        wsum[blockIdx.y * N_TOT + grow] = s[r * 16 + e];
      }
  }
}

// ---- 4. per-row chunk merge + loss partial per block ----
__global__ void finish_kernel(const float* __restrict__ wsum,
                              const float* __restrict__ pos2, float* __restrict__ partial) {
  const int i = blockIdx.x * blockDim.x + threadIdx.x;   // row, exactly 8192 threads
  float S = 0.f;
  #pragma unroll
  for (int c = 0; c < NC; ++c) S += wsum[c * N_TOT + i];
  float lse2 = SHIFT2 + log2f(S);
  float contrib = (lse2 - pos2[i]) * (LN2F / (float)N_TOT);

  #pragma unroll
  for (int d = 32; d >= 1; d >>= 1) contrib += __shfl_down(contrib, d, 64);
  __shared__ float red[4];
  if ((threadIdx.x & 63) == 0) red[threadIdx.x >> 6] = contrib;
  __syncthreads();
  if (threadIdx.x == 0) partial[blockIdx.x] = red[0] + red[1] + red[2] + red[3];
}

__global__ void final_kernel(const float* __restrict__ partial, float* __restrict__ out) {
  int l = threadIdx.x;
  float v = (l < 32) ? partial[l] : 0.f;
  #pragma unroll
  for (int d = 32; d >= 1; d >>= 1) v += __shfl_down(v, d, 64);
  if (l == 0) out[0] = v;
}

extern "C" void kernel_launch(void* const* d_in, const int* in_sizes, int n_in,
                              void* d_out, int out_size, void* d_ws, size_t ws_size,
                              hipStream_t stream) {
  const float* hi = (const float*)d_in[0];
  const float* hj = (const float*)d_in[1];
  float* out = (float*)d_out;
  char* ws = (char*)d_ws;

  ushort* hb    = (ushort*)(ws);                       // 4 MB bf16 h
  float*  wsum  = (float*)(ws + 4194304);              // 512 KB  [NC][N] shifted sums
  float*  pos2  = (float*)(ws + 4194304 + 524288);     // 32 KB   positive logits
  float*  part  = (float*)(ws + 4194304 + 524288 + 32768); // 128 B block partials

  conv_kernel<<<N_TOT * DIM / 4 / 256, 256, 0, stream>>>(hi, hj, hb);
  pos_kernel<<<N_TOT / 4, 256, 0, stream>>>(hb, pos2);
  dim3 g1(N_TOT / BM, NC);
  lse_stage1<<<g1, 256, 0, stream>>>(hb, wsum);
  finish_kernel<<<N_TOT / 256, 256, 0, stream>>>(wsum, pos2, part);
  final_kernel<<<1, 64, 0, stream>>>(part, out);
}